// Round 7
// baseline (612.945 us; speedup 1.0000x reference)
//
#include <hip/hip_runtime.h>
#include <hip/hip_bf16.h>

// Dims: B=256, Nv=196, Lt=32, Ci=768, Ct=512, H=12, D=64
// M1 = 50176 (=392*128), M2 = 8192 (=64*128), N = 768 (=6*128)

typedef __attribute__((ext_vector_type(8))) short bf16x8;
typedef __attribute__((ext_vector_type(4))) float f32x4;

__device__ __forceinline__ float bf2f(unsigned short u) {
    return __uint_as_float(((unsigned int)u) << 16);
}
__device__ __forceinline__ unsigned short f2bf(float f) {
    unsigned int x = __float_as_uint(f);
    unsigned int r = (x + 0x7FFFu + ((x >> 16) & 1u)) >> 16;  // RNE
    return (unsigned short)r;
}

// async global->LDS, 16B/lane. LDS dest is wave-uniform base + lane*16.
#define GLOAD_LDS16(gp, lp)                                                    \
    __builtin_amdgcn_global_load_lds(                                          \
        (__attribute__((address_space(1))) void*)(gp),                         \
        (__attribute__((address_space(3))) void*)(lp), 16, 0, 0)

// ------ fused: fp32->bf16 converts (vis+txt) AND all 4 weight transposes ---
// blocks [0, 41728): cvt (vis then txt); [41728, 43648): 32x32 transposes.
__global__ void cvt_tr_kernel(const float* __restrict__ vis, unsigned short* __restrict__ Abf,
                              const float* __restrict__ txt, unsigned short* __restrict__ Tbf,
                              const float* __restrict__ Wq, unsigned short* __restrict__ Wqt,
                              const float* __restrict__ Wk, unsigned short* __restrict__ Wkt,
                              const float* __restrict__ Wv, unsigned short* __restrict__ Wvt,
                              const float* __restrict__ W1, unsigned short* __restrict__ W1t) {
    __shared__ float tile[32][33];
    int id = blockIdx.x;
    if (id < 41728) {   // converts: 9,633,792 vis + 1,048,576 txt float4s
        int i = id * 256 + threadIdx.x;
        const float* in = vis; unsigned short* out = Abf;
        if (i >= 9633792) { i -= 9633792; in = txt; out = Tbf; }
        float4 v = ((const float4*)in)[i];
        ushort4 o;
        o.x = f2bf(v.x); o.y = f2bf(v.y); o.z = f2bf(v.z); o.w = f2bf(v.w);
        ((ushort4*)out)[i] = o;
        return;
    }
    id -= 41728;
    const float* W; unsigned short* Wt; int K;
    if (id < 576)       { W = Wq; Wt = Wqt; K = 768; }
    else if (id < 960)  { id -= 576;  W = Wk; Wt = Wkt; K = 512; }
    else if (id < 1344) { id -= 960;  W = Wv; Wt = Wvt; K = 512; }
    else                { id -= 1344; W = W1; Wt = W1t; K = 768; }
    int n0 = (id % 24) * 32, k0 = (id / 24) * 32;
    int tx = threadIdx.x & 31, ty = threadIdx.x >> 5;  // 256 thr: ty 0..7
    #pragma unroll
    for (int r = ty; r < 32; r += 8)
        tile[r][tx] = W[(size_t)(k0 + r) * 768 + n0 + tx];
    __syncthreads();
    #pragma unroll
    for (int r = ty; r < 32; r += 8)
        Wt[(size_t)(n0 + r) * K + k0 + tx] = f2bf(tile[tx][r]);
}

// ---------------- 128x128 bf16 MFMA GEMM (m97 2-phase, proven schedule) ----
// Loop byte-identical to R4-R6 (conflicts 0, WRITE ideal). This round's
// change is OCCUPANCY ONLY: launch_bounds(256,5) -> 5 blocks/CU (LDS
// 5 x 32KB = 160KB exactly; VGPR 56 << 2048/5). R6 analysis: 1985 cy/tile
// vs pipe floors (MFMA 620, LDS 762) -> stall-bound; the m114 implicit
// inter-block overlap is the only lever that has moved this structure,
// and the 5th block slot was free. Also cuts grid quantization:
// qkv 3120/1280=2.4 (was 3.05), gelu 2352/1280=1.8 (was 2.3).
template<int KTOT, int GELU, int MTILES>
__device__ __forceinline__
void gemm_body(int id, const unsigned short* __restrict__ A,
               const unsigned short* __restrict__ Bt,
               const float* __restrict__ bias,
               unsigned short* __restrict__ C,
               const float* __restrict__ W2,
               float* __restrict__ part,
               unsigned short* As, unsigned short* Bs) {
    constexpr int NT = KTOT / 64;
    constexpr int PAN = 4096;          // 128 rows x 32 shorts (one k-panel)
    const int tid = threadIdx.x;
    const int lane = tid & 63, wave = tid >> 6;        // 4 waves, 2x2
    const int wm = (wave >> 1) * 64, wn = (wave & 1) * 64;
    const int lr = lane & 15, quad = lane >> 4;

    // XCD-chunked tile mapping (grid % 8 == 0 for all uses)
    const int xcd = id & 7, local = id >> 3;
    const int nt = local % 6, mt = xcd * (MTILES / 8) + local / 6;
    const size_t m0 = (size_t)mt * 128;
    const int n0 = nt * 128;

    // read-side swizzled addressing (row*32 shorts + XORed 8-short slot)
    const int slotoff = ((quad ^ (((lr >> 3) & 1) << 1)) << 3);
    const int aBase = (wm + lr) * 32 + slotoff;        // + i*512 + kk*PAN
    const int bBase = (wn + lr) * 32 + slotoff;

    // staging source (pre-swizzled global): lane -> row lane>>2, slot
    // (lane&3)^(((lane>>5)&1)<<1); LDS dest linear; involution of read XOR.
    const int sg = (lane & 3) ^ (((lane >> 5) & 1) << 1);
    const unsigned short* gA = A + (m0 + (lane >> 2)) * (size_t)KTOT + sg * 8;
    const unsigned short* gB = Bt + ((size_t)n0 + (lane >> 2)) * KTOT + sg * 8;
    const int sr = wave * 32;   // wave's 32-row strip (2 x 16-row blocks)

    f32x4 acc[4][4] = {};

    for (int t = 0; t < NT; ++t) {
        #pragma unroll
        for (int p = 0; p < 2; ++p) {
            #pragma unroll
            for (int q = 0; q < 2; ++q) {
                const int r0 = sr + q * 16;
                GLOAD_LDS16(gA + (size_t)r0 * KTOT + t * 64 + p * 32,
                            As + p * PAN + r0 * 32);
                GLOAD_LDS16(gB + (size_t)r0 * KTOT + t * 64 + p * 32,
                            Bs + p * PAN + r0 * 32);
            }
        }
        __syncthreads();   // compiler drains vmcnt(0) before barrier
        #pragma unroll
        for (int kk = 0; kk < 2; ++kk) {
            bf16x8 fa[4], fb[4];
            #pragma unroll
            for (int i = 0; i < 4; ++i)
                fa[i] = *(const bf16x8*)(As + kk * PAN + aBase + i * 512);
            #pragma unroll
            for (int j = 0; j < 4; ++j)
                fb[j] = *(const bf16x8*)(Bs + kk * PAN + bBase + j * 512);
            #pragma unroll
            for (int i = 0; i < 4; ++i)
                #pragma unroll
                for (int j = 0; j < 4; ++j)
                    acc[i][j] = __builtin_amdgcn_mfma_f32_16x16x32_bf16(
                        fa[i], fb[j], acc[i][j], 0, 0, 0);
        }
        __syncthreads();
    }

    // epilogue: C/D layout col=lane&15, row=quad*4+reg [m89-verified]
    float bvv[4];
    #pragma unroll
    for (int j = 0; j < 4; ++j)
        bvv[j] = bias[n0 + wn + j * 16 + lr];

    if (GELU) {
        // fused mlp2 partials (race-free slots, validated R6):
        // slot part[row*24 + nt*4 + wn*2 + {0,1}] owned by exactly one wave.
        float w2a[4], w2b[4];
        #pragma unroll
        for (int j = 0; j < 4; ++j) {
            int col = n0 + wn + j * 16 + lr;
            w2a[j] = W2[col * 2];
            w2b[j] = W2[col * 2 + 1];
        }
        const int sbase = nt * 4 + (wave & 1) * 2;   // slot: nt(6) x wn(2) x 2
        #pragma unroll
        for (int i = 0; i < 4; ++i) {
            #pragma unroll
            for (int r2 = 0; r2 < 4; ++r2) {
                size_t row = m0 + wm + i * 16 + quad * 4 + r2;
                float p0 = 0.f, p1 = 0.f;
                #pragma unroll
                for (int j = 0; j < 4; ++j) {
                    float x = acc[i][j][r2] + bvv[j];
                    x = x / (1.0f + __expf(-1.702f * x));  // quick_gelu
                    p0 += x * w2a[j];
                    p1 += x * w2b[j];
                }
                #pragma unroll
                for (int off = 1; off < 16; off <<= 1) {
                    p0 += __shfl_xor(p0, off);
                    p1 += __shfl_xor(p1, off);
                }
                if (lr == 0) {
                    float* pp = part + row * 24 + sbase;
                    pp[0] = p0;
                    pp[1] = p1;
                }
            }
        }
    } else {
        // j innermost: each row's 128B span completes in 4 consecutive stores
        #pragma unroll
        for (int i = 0; i < 4; ++i) {
            #pragma unroll
            for (int r2 = 0; r2 < 4; ++r2) {
                size_t row = m0 + wm + i * 16 + quad * 4 + r2;
                unsigned short* cp = C + row * 768 + n0 + wn + lr;
                #pragma unroll
                for (int j = 0; j < 4; ++j)
                    cp[j * 16] = f2bf(acc[i][j][r2] + bvv[j]);
            }
        }
    }
}

// Q, K and V projections in ONE dispatch (all inputs ready after cvt_tr).
// Sub-grids: [0,2352) Q (2352%8==0), [2352,2736) K, [2736,3120) V.
// Q (longest blocks) dispatched first: longest-first reduces makespan tail.
__global__ __launch_bounds__(256, 5)
void gemm_qkv_kernel(const unsigned short* __restrict__ Abf,
                     const unsigned short* __restrict__ Wqt,
                     const float* __restrict__ bq,
                     unsigned short* __restrict__ Qbf,
                     const unsigned short* __restrict__ Tbf,
                     const unsigned short* __restrict__ Wkt,
                     const float* __restrict__ bk,
                     unsigned short* __restrict__ Kbf,
                     const unsigned short* __restrict__ Wvt,
                     const float* __restrict__ bv,
                     unsigned short* __restrict__ Vbf) {
    __shared__ unsigned short As[2 * 4096];   // 16 KB
    __shared__ unsigned short Bs[2 * 4096];   // 16 KB (32 KB total: 5/CU fit)
    const int id = blockIdx.x;
    if (id < 2352)
        gemm_body<768, 0, 392>(id, Abf, Wqt, bq, Qbf, nullptr, nullptr, As, Bs);
    else if (id < 2736)
        gemm_body<512, 0, 64>(id - 2352, Tbf, Wkt, bk, Kbf, nullptr, nullptr, As, Bs);
    else
        gemm_body<512, 0, 64>(id - 2736, Tbf, Wvt, bv, Vbf, nullptr, nullptr, As, Bs);
}

// GELU GEMM with fused mlp2 partials (no C output at all)
__global__ __launch_bounds__(256, 5)
void gemm_gelu_kernel(const unsigned short* __restrict__ A,
                      const unsigned short* __restrict__ Bt,
                      const float* __restrict__ bias,
                      const float* __restrict__ W2,
                      float* __restrict__ part) {
    __shared__ unsigned short As[2 * 4096];
    __shared__ unsigned short Bs[2 * 4096];
    gemm_body<768, 1, 392>(blockIdx.x, A, Bt, bias, nullptr, W2, part, As, Bs);
}

// ---------------- final reduce: 24 partials/row -> logits; rel fill --------
__global__ __launch_bounds__(256)
void mlp2_reduce_kernel(const float* __restrict__ part,
                        const float* __restrict__ b2,
                        float* __restrict__ out) {
    int row = blockIdx.x * 256 + threadIdx.x;   // 196 blocks x 256 = 50176
    const float4* p = (const float4*)(part + (size_t)row * 24);
    float a0 = 0.f, a1 = 0.f;
    #pragma unroll
    for (int i = 0; i < 6; ++i) {
        float4 v = p[i];
        a0 += v.x + v.z;
        a1 += v.y + v.w;
    }
    out[row * 2]      = a0 + b2[0];
    out[row * 2 + 1]  = a1 + b2[1];
    // rel_BN: softmax rows sum to 1 -> mean over Lt = 1/32, mean over H = 1/32
    out[100352 + row] = 0.03125f;
}

// ---------------- MFMA attention: one block per (b,h), 4 waves -------------
// LDS 23.3KB -> 6 blocks/CU fit; bounds(256,6): 3072/(256x6)=2 rounds (was 3).
__global__ __launch_bounds__(256, 6)
void attn_mfma_kernel(const unsigned short* __restrict__ Q,
                      const unsigned short* __restrict__ Kb,
                      const unsigned short* __restrict__ Vb,
                      unsigned short* __restrict__ RF) {
    constexpr int KS = 72;  // Ks row stride
    constexpr int VS = 34;  // Vt row stride
    constexpr int PS = 40;  // P row stride
    constexpr int CS = 72;  // ctx row stride
    __shared__ unsigned short Ks[32 * KS];      // K rows  [l][d]
    __shared__ unsigned short Vt[64 * VS];      // V^T     [d][l]
    __shared__ unsigned short Pb[4][16 * PS];   // per-wave P  [m][l]
    __shared__ unsigned short Cb[4][16 * CS];   // per-wave ctx[m][d]
    const int tid = threadIdx.x;
    const int b = blockIdx.x / 12, h = blockIdx.x % 12;
    const int lane = tid & 63, wave = tid >> 6;
    const int lr = lane & 15, quad = lane >> 4;

    {   // stage K rows + V transposed (bf16, one-time)
        int l = tid >> 3, d8 = (tid & 7) * 8;
        size_t base = ((size_t)b * 32 + l) * 768 + (size_t)h * 64 + d8;
        bf16x8 kv = *(const bf16x8*)(Kb + base);
        bf16x8 vv = *(const bf16x8*)(Vb + base);
        *(bf16x8*)(Ks + l * KS + d8) = kv;
        #pragma unroll
        for (int j = 0; j < 8; ++j)
            Vt[(d8 + j) * VS + l] = (unsigned short)vv[j];
    }
    __syncthreads();

    bf16x8 fbK[2][2];
    #pragma unroll
    for (int n = 0; n < 2; ++n)
        #pragma unroll
        for (int ks = 0; ks < 2; ++ks)
            fbK[n][ks] = *(const bf16x8*)(Ks + (n * 16 + lr) * KS + ks * 32 + quad * 8);
    bf16x8 fbV[4];
    #pragma unroll
    for (int d = 0; d < 4; ++d)
        fbV[d] = *(const bf16x8*)(Vt + (d * 16 + lr) * VS + quad * 8);

    const size_t qbase = (size_t)b * 196 * 768 + (size_t)h * 64;

    for (int t = wave; t < 13; t += 4) {   // 13 tiles of 16 rows cover 196
        const int m0 = t * 16;
        int qrow = m0 + lr; if (qrow > 195) qrow = 195;  // clamp tail dups
        const unsigned short* qp = Q + qbase + (size_t)qrow * 768;
        bf16x8 fa0 = *(const bf16x8*)(qp + quad * 8);
        bf16x8 fa1 = *(const bf16x8*)(qp + 32 + quad * 8);

        // T14 issue-early: prefetch residual rows now, consumed at tile end.
        bf16x8 rv[2]; int rrow[2];
        #pragma unroll
        for (int i = 0; i < 2; ++i) {
            int c2 = lane + i * 64;
            rrow[i] = m0 + (c2 >> 3);
            if (rrow[i] < 196)
                rv[i] = *(const bf16x8*)(RF + qbase + (size_t)rrow[i] * 768 +
                                         (c2 & 7) * 8);
        }

        f32x4 s0 = {}, s1 = {};
        s0 = __builtin_amdgcn_mfma_f32_16x16x32_bf16(fa0, fbK[0][0], s0, 0, 0, 0);
        s0 = __builtin_amdgcn_mfma_f32_16x16x32_bf16(fa1, fbK[0][1], s0, 0, 0, 0);
        s1 = __builtin_amdgcn_mfma_f32_16x16x32_bf16(fa0, fbK[1][0], s1, 0, 0, 0);
        s1 = __builtin_amdgcn_mfma_f32_16x16x32_bf16(fa1, fbK[1][1], s1, 0, 0, 0);

        float p0[4], p1[4], m4[4], s4[4];
        #pragma unroll
        for (int r = 0; r < 4; ++r) {
            p0[r] = s0[r] * 0.125f;
            p1[r] = s1[r] * 0.125f;
            m4[r] = fmaxf(p0[r], p1[r]);
        }
        #pragma unroll
        for (int off = 1; off < 16; off <<= 1)
            #pragma unroll
            for (int r = 0; r < 4; ++r)
                m4[r] = fmaxf(m4[r], __shfl_xor(m4[r], off));
        #pragma unroll
        for (int r = 0; r < 4; ++r) {
            p0[r] = __expf(p0[r] - m4[r]);
            p1[r] = __expf(p1[r] - m4[r]);
            s4[r] = p0[r] + p1[r];
        }
        #pragma unroll
        for (int off = 1; off < 16; off <<= 1)
            #pragma unroll
            for (int r = 0; r < 4; ++r)
                s4[r] += __shfl_xor(s4[r], off);
        #pragma unroll
        for (int r = 0; r < 4; ++r) {
            float inv = __builtin_amdgcn_rcpf(s4[r]);
            unsigned short* pr = &Pb[wave][(quad * 4 + r) * PS];
            pr[lr]      = f2bf(p0[r] * inv);
            pr[16 + lr] = f2bf(p1[r] * inv);
        }

        bf16x8 fap = *(const bf16x8*)(&Pb[wave][lr * PS + quad * 8]);
        f32x4 c[4];
        #pragma unroll
        for (int d = 0; d < 4; ++d) {
            f32x4 z = {};
            c[d] = __builtin_amdgcn_mfma_f32_16x16x32_bf16(fap, fbV[d], z, 0, 0, 0);
        }
        #pragma unroll
        for (int d = 0; d < 4; ++d)
            #pragma unroll
            for (int r = 0; r < 4; ++r)
                Cb[wave][(quad * 4 + r) * CS + d * 16 + lr] = f2bf(c[d][r]);
        #pragma unroll
        for (int i = 0; i < 2; ++i) {
            int c2 = lane + i * 64;
            int row = c2 >> 3, col8 = (c2 & 7) * 8;
            if (rrow[i] < 196) {
                bf16x8 cv = *(const bf16x8*)(&Cb[wave][row * CS + col8]);
                unsigned short* gp = RF + qbase + (size_t)rrow[i] * 768 + col8;
                bf16x8 ov;
                #pragma unroll
                for (int j = 0; j < 8; ++j)
                    ov[j] = (short)f2bf(bf2f((unsigned short)cv[j]) +
                                        bf2f((unsigned short)rv[i][j]));
                *(bf16x8*)gp = ov;
            }
        }
    }
}

extern "C" void kernel_launch(void* const* d_in, const int* in_sizes, int n_in,
                              void* d_out, int out_size, void* d_ws, size_t ws_size,
                              hipStream_t stream) {
    const float* vis = (const float*)d_in[0];
    const float* txt = (const float*)d_in[1];
    const float* Wq  = (const float*)d_in[2];
    const float* bq  = (const float*)d_in[3];
    const float* Wk  = (const float*)d_in[4];
    const float* bk  = (const float*)d_in[5];
    const float* Wv  = (const float*)d_in[6];
    const float* bv  = (const float*)d_in[7];
    const float* W1  = (const float*)d_in[8];
    const float* b1  = (const float*)d_in[9];
    const float* W2  = (const float*)d_in[10];
    const float* b2  = (const float*)d_in[11];
    float* out = (float*)d_out;

    char* w = (char*)d_ws;
    unsigned short* Abf = (unsigned short*)(w);              // 77,070,336 B (vis bf16; becomes "fused")
    unsigned short* Tbf = (unsigned short*)(w + 77070336);   //  8,388,608 B (text bf16)
    unsigned short* Wqt = (unsigned short*)(w + 85458944);   //  1,179,648 B
    unsigned short* Wkt = (unsigned short*)(w + 86638592);   //    786,432 B
    unsigned short* Wvt = (unsigned short*)(w + 87425024);   //    786,432 B
    unsigned short* W1t = (unsigned short*)(w + 88211456);   //  1,179,648 B
    unsigned short* Qbf = (unsigned short*)(w + 89391104);   // 77,070,336 B
    unsigned short* Kbf = (unsigned short*)(w + 166461440);  // 12,582,912 B
    unsigned short* Vbf = (unsigned short*)(w + 179044352);  // 12,582,912 B
    // mlp2 partials: 50176 rows x 24 f32 = 4,816,896 B. Reuses Kbf's region
    // (K dead after attn; GELU GEMM + reduce both run after attn).
    float* Part = (float*)(w + 166461440);

    // 41,728 cvt blocks + 1,920 transpose blocks, one launch
    cvt_tr_kernel<<<43648, 256, 0, stream>>>(vis, Abf, txt, Tbf,
                                             Wq, Wqt, Wk, Wkt,
                                             Wv, Wvt, W1, W1t);

    gemm_qkv_kernel<<<3120, 256, 0, stream>>>(Abf, Wqt, bq, Qbf,
                                              Tbf, Wkt, bk, Kbf,
                                              Wvt, bv, Vbf);

    attn_mfma_kernel<<<3072, 256, 0, stream>>>(Qbf, Kbf, Vbf, Abf);

    // GELU GEMM writes race-free mlp2 partials into Part (ex-Kbf region)
    gemm_gelu_kernel<<<2352, 256, 0, stream>>>(Abf, W1t, b1, W2, Part);

    mlp2_reduce_kernel<<<196, 256, 0, stream>>>(Part, b2, out);
}